// Round 5
// baseline (95.385 us; speedup 1.0000x reference)
//
#include <hip/hip_runtime.h>

#define NB 128
#define NL 2048
#define NH 256
#define NSEG 16
#define SEGLEN (NL / NSEG)   // 128
#define RCHUNK 16            // timesteps per reduce-chunk in pass3
#define NCH (SEGLEN / RCHUNK)
#define PBPITCH 9            // uints per channel row in pbuf (2-way banks)
#define CHUNK 32             // fallback kernel chunking
#define NCHUNK (NL / CHUNK)
#define WORDS (CHUNK * 3)

typedef float f32x2 __attribute__((ext_vector_type(2)));
typedef __fp16 f16x2 __attribute__((ext_vector_type(2)));   // matches cvt_pkrtz return type

__device__ __forceinline__ float fexp2(float v) { return __builtin_amdgcn_exp2f(v); }
__device__ __forceinline__ float frcp(float v)  { return __builtin_amdgcn_rcpf(v); }

__device__ __forceinline__ f32x2 pkfma(f32x2 a, f32x2 b, f32x2 c) {
#if __has_builtin(__builtin_elementwise_fma)
    return __builtin_elementwise_fma(a, b, c);   // -> v_pk_fma_f32
#else
    f32x2 r; r.x = fmaf(a.x, b.x, c.x); r.y = fmaf(a.y, b.y, c.y); return r;
#endif
}
__device__ __forceinline__ f32x2 splat2(float v) { f32x2 r; r.x = v; r.y = v; return r; }

union U32H2 { unsigned int u; f16x2 h; };

// ---------------------------------------------------------------------------
// Fold K=3 projection through Wz/Wh, pre-scaled by exp2 constants.
// 4 blocks x 256 threads: (jj = tid&63 -> channel, hs = tid>>6 -> h-slice).
// ---------------------------------------------------------------------------
__global__ __launch_bounds__(256) void fold_kernel(
        const float* __restrict__ Wp, const float* __restrict__ bp,
        const float* __restrict__ Wz, const float* __restrict__ bz,
        const float* __restrict__ Wh, const float* __restrict__ bh,
        float* __restrict__ wsW) {
    const int tid = threadIdx.x;
    const int jj = tid & 63;
    const int hs = tid >> 6;                 // 0..3
    const int j = blockIdx.x * 64 + jj;
    float mz0 = 0.f, mz1 = 0.f, mz2 = 0.f, cz = 0.f;
    float mh0 = 0.f, mh1 = 0.f, mh2 = 0.f, ch = 0.f;
#pragma unroll 8
    for (int i = 0; i < 64; ++i) {
        const int h = hs * 64 + i;
        const float wz = Wz[h * NH + j];
        const float wh = Wh[h * NH + j];
        const float p0 = Wp[h];
        const float p1 = Wp[NH + h];
        const float p2 = Wp[2 * NH + h];
        const float bb = bp[h];
        mz0 = fmaf(p0, wz, mz0); mz1 = fmaf(p1, wz, mz1); mz2 = fmaf(p2, wz, mz2);
        cz  = fmaf(bb, wz, cz);
        mh0 = fmaf(p0, wh, mh0); mh1 = fmaf(p1, wh, mh1); mh2 = fmaf(p2, wh, mh2);
        ch  = fmaf(bb, wh, ch);
    }
    __shared__ float red[256][9];            // pad 9: 2-way banks
    red[tid][0] = mz0; red[tid][1] = mz1; red[tid][2] = mz2; red[tid][3] = cz;
    red[tid][4] = mh0; red[tid][5] = mh1; red[tid][6] = mh2; red[tid][7] = ch;
    __syncthreads();
    if (tid < 64) {
        float v[8];
#pragma unroll
        for (int k = 0; k < 8; ++k)
            v[k] = red[tid][k] + red[tid + 64][k] + red[tid + 128][k] + red[tid + 192][k];
        v[3] += bz[j];
        v[7] += bh[j];
        const float SZ = -1.4426950408889634f;   // -log2(e)
        const float SH = -2.8853900817779268f;   // -2*log2(e)
        float4* w4 = (float4*)(wsW + j * 8);
        w4[0] = make_float4(v[0] * SZ, v[1] * SZ, v[2] * SZ, v[3] * SZ);
        w4[1] = make_float4(v[4] * SH, v[5] * SH, v[6] * SH, v[7] * SH);
    }
}

// Gate math for 2 timesteps (packed). Inputs: x floats via compile-time-indexed
// uniform array. Outputs av (= 1-z) and bv (= z*tanh) pairs.
#define GATE2(XQ, U0, AV, BV)                                                   \
    {                                                                           \
        const float* xf_ = (const float*)(XQ);                                  \
        f32x2 xx_ = { xf_[6*(U0)+0], xf_[6*(U0)+3] };                           \
        f32x2 xy_ = { xf_[6*(U0)+1], xf_[6*(U0)+4] };                           \
        f32x2 xz_ = { xf_[6*(U0)+2], xf_[6*(U0)+5] };                           \
        const f32x2 s1_ = pkfma(xx_, wax, pkfma(xy_, way, pkfma(xz_, waz, waw)));\
        const f32x2 s2_ = pkfma(xx_, wbx, pkfma(xy_, wby, pkfma(xz_, wbz, wbw)));\
        f32x2 e1_, e2_;                                                         \
        e1_.x = fexp2(s1_.x); e1_.y = fexp2(s1_.y);                             \
        e2_.x = fexp2(s2_.x); e2_.y = fexp2(s2_.y);                             \
        const f32x2 d2_ = e2_ + 1.f;                                            \
        const f32x2 e1d2_ = e1_ * d2_;                                          \
        const f32x2 dd_ = e1d2_ + d2_;                                          \
        const float rp_ = frcp(dd_.x * dd_.y);                                  \
        f32x2 rr_; rr_.x = dd_.y * rp_; rr_.y = dd_.x * rp_;                    \
        AV = e1d2_ * rr_;                                                       \
        BV = (1.f - e2_) * rr_;                                                 \
    }

// ---------------------------------------------------------------------------
// Pass 1: per-(batch, segment) blocks of 256 threads (thread = channel).
// Segment composite (A, B): h_end = A*h_start + B. x via scalar loads.
// ---------------------------------------------------------------------------
__global__ __launch_bounds__(256, 8) void pass1_seg(
        const float* __restrict__ x, const float* __restrict__ wsW,
        float* __restrict__ Aarr, float* __restrict__ Barr) {
    const int tid = threadIdx.x;
    const int b = blockIdx.x >> 4;
    const int s = blockIdx.x & (NSEG - 1);

    const float4* wv = (const float4*)(wsW + tid * 8);
    const float4 wA4 = wv[0];
    const float4 wB4 = wv[1];
    const f32x2 wax = splat2(wA4.x), way = splat2(wA4.y), waz = splat2(wA4.z), waw = splat2(wA4.w);
    const f32x2 wbx = splat2(wB4.x), wby = splat2(wB4.y), wbz = splat2(wB4.z), wbw = splat2(wB4.w);

    // block-uniform x base -> scalar loads
    const float4* xs4 = (const float4*)(x + ((size_t)b * NL + (size_t)s * SEGLEN) * 3);

    float A = 1.f, Bacc = 0.f;
    for (int c = 0; c < NCH; ++c) {
        float4 xq[12];                       // 48 floats = 16 timesteps (uniform/SGPR)
#pragma unroll
        for (int i = 0; i < 12; ++i) xq[i] = xs4[c * 12 + i];
#pragma unroll
        for (int u0 = 0; u0 < 8; ++u0) {
            f32x2 av, bv;
            GATE2(xq, u0, av, bv);
            Bacc = fmaf(av.x, Bacc, bv.x);
            Bacc = fmaf(av.y, Bacc, bv.y);
            A *= av.x * av.y;
        }
    }
    const size_t o = ((size_t)b * NSEG + s) * NH + tid;
    Aarr[o] = A;
    Barr[o] = Bacc;
}

// ---------------------------------------------------------------------------
// Pass 3: per-(batch, segment) blocks. Computes its own segment prefix from
// (A,B), recomputes in-segment recurrence, emits preds. Pred-reduction over
// 256 channels via f16x2-packed LDS transpose.
// ---------------------------------------------------------------------------
__global__ __launch_bounds__(256, 8) void pass3_pred(
        const float* __restrict__ x, const float* __restrict__ wsW,
        const float* __restrict__ Wg, const float* __restrict__ bg,
        const float* __restrict__ Aarr, const float* __restrict__ Barr,
        float* __restrict__ out) {
    const int tid = threadIdx.x;
    const int b = blockIdx.x >> 4;
    const int s = blockIdx.x & (NSEG - 1);

    const float4* wv = (const float4*)(wsW + tid * 8);
    const float4 wA4 = wv[0];
    const float4 wB4 = wv[1];
    const f32x2 wax = splat2(wA4.x), way = splat2(wA4.y), waz = splat2(wA4.z), waw = splat2(wA4.w);
    const f32x2 wbx = splat2(wB4.x), wby = splat2(wB4.y), wbz = splat2(wB4.z), wbw = splat2(wB4.w);
    const float wg = Wg[tid];
    const float bgv = bg[0];

    // ---- segment-start state: prefix over earlier segments' (A,B) ----
    float h = 0.f;
    {
        const size_t pbase = (size_t)b * NSEG * NH + tid;
        for (int k0 = 0; k0 < NSEG; k0 += 8) {
            float Ak[8], Bk[8];
#pragma unroll
            for (int k = 0; k < 8; ++k) {
                const int kk = k0 + k;                 // uniform predicate
                Ak[k] = (kk < s) ? Aarr[pbase + (size_t)kk * NH] : 1.f;
                Bk[k] = (kk < s) ? Barr[pbase + (size_t)kk * NH] : 0.f;
            }
#pragma unroll
            for (int k = 0; k < 8; ++k) h = fmaf(Ak[k], h, Bk[k]);
        }
    }

    const float4* xs4 = (const float4*)(x + ((size_t)b * NL + (size_t)s * SEGLEN) * 3);

    __shared__ unsigned int pbuf[NH * PBPITCH];   // f16x2 pairs, 9216 B
    __shared__ float part2[32][18];               // [grp][t]
    __shared__ float part3[4][17];

    const int q   = tid & 7;                 // stage2: timestep-pair index
    const int grp = tid >> 3;                // stage2: channel group (8 ch)

    for (int c = 0; c < NCH; ++c) {
        float4 xq[12];
#pragma unroll
        for (int i = 0; i < 12; ++i) xq[i] = xs4[c * 12 + i];
        float p[RCHUNK];
#pragma unroll
        for (int u0 = 0; u0 < 8; ++u0) {
            f32x2 av, bv;
            GATE2(xq, u0, av, bv);
            p[2 * u0] = h * wg;              // pred uses h BEFORE update
            h = fmaf(av.x, h, bv.x);
            p[2 * u0 + 1] = h * wg;
            h = fmaf(av.y, h, bv.y);
        }
        // stage 1: pack pairs to f16x2, write 8 b32 (banks 2-way = free)
#pragma unroll
        for (int v = 0; v < 8; ++v) {
            U32H2 pk; pk.h = __builtin_amdgcn_cvt_pkrtz(p[2 * v], p[2 * v + 1]);
            pbuf[tid * PBPITCH + v] = pk.u;
        }
        __syncthreads();
        // stage 2: each thread sums 8 channels for one t-pair (pk_add_f16)
        f16x2 acc2 = (f16x2)0.f;
#pragma unroll
        for (int j = 0; j < 8; ++j) {
            const int c2 = grp * 8 + ((j + grp) & 7);    // rotation
            U32H2 rd; rd.u = pbuf[c2 * PBPITCH + q];
            acc2 += rd.h;
        }
        {
            f32x2 pr; pr.x = (float)acc2.x; pr.y = (float)acc2.y;
            *(f32x2*)&part2[grp][2 * q] = pr;            // b64 store
        }
        __syncthreads();
        // stage 3a: wave 0 reduces 32 groups -> 4 quads
        if (tid < 64) {
            const int t2 = tid & 15, quad = tid >> 4;
            float a3 = 0.f;
#pragma unroll
            for (int g2 = 0; g2 < 8; ++g2)
                a3 += part2[quad * 8 + g2][t2];
            part3[quad][t2] = a3;
            // stage 3b: final 4-way + bias, straight to out (intra-wave, no barrier)
            if (tid < 16) {
                const float o = part3[0][tid] + part3[1][tid]
                              + part3[2][tid] + part3[3][tid] + bgv;
                out[(size_t)b * NL + (size_t)s * SEGLEN + c * RCHUNK + tid] = o;
            }
        }
        // pbuf overwrite (next stage1) is fenced for all waves by the second
        // barrier above; part2 rewrite happens only after the next first barrier.
    }
}

// ---------------------------------------------------------------------------
// Fallback (ws too small): monolithic scan, 128 blocks x 256 thr.
// ---------------------------------------------------------------------------
__global__ __launch_bounds__(256) void scan_kernel_nows(
        const float* __restrict__ x, const float* __restrict__ wsW,
        const float* __restrict__ Wg, const float* __restrict__ bg,
        float* __restrict__ out) {
    const int tid  = threadIdx.x;
    const int lane = tid & 63;
    const int wid  = tid >> 6;
    const int b = blockIdx.x;

    const float4* wv = (const float4*)(wsW + tid * 8);
    const float4 wA = wv[0];
    const float4 wB = wv[1];
    const float  wg = Wg[tid];
    const float  bgv = bg[0];

    const float* xb = x + (size_t)b * (NL * 3);

    __shared__ float4 xbuf[2][CHUNK];
    __shared__ float  predbuf[2][4][CHUNK];
    float* xbf = (float*)xbuf;

    const int sw = tid;
    const int sidx = (sw / 3) * 4 + (sw % 3);

    if (tid < WORDS) xbf[sidx] = xb[sw];
    __syncthreads();

    float h = 0.f;
    for (int c = 0; c < NCHUNK; ++c) {
        const int cur = c & 1;
        float nv = 0.f;
        if (tid < WORDS && c + 1 < NCHUNK) nv = xb[(c + 1) * WORDS + sw];

        float p[CHUNK];
        const float4* xc = xbuf[cur];
#pragma unroll
        for (int t = 0; t < CHUNK; ++t) {
            const float4 xv = xc[t];
            const float e1 = fexp2(fmaf(xv.x, wA.x, fmaf(xv.y, wA.y, fmaf(xv.z, wA.z, wA.w))));
            const float e2 = fexp2(fmaf(xv.x, wB.x, fmaf(xv.y, wB.y, fmaf(xv.z, wB.z, wB.w))));
            const float d2 = 1.f + e2;
            const float e1d2 = e1 * d2;
            const float r  = frcp(e1d2 + d2);
            p[t] = h * wg;
            h = fmaf(e1d2 * r, h, (1.f - e2) * r);
        }
#pragma unroll
        for (int t = 0; t < CHUNK; ++t) {
            float v = p[t];
            v += __shfl_xor(v, 1, 64);
            v += __shfl_xor(v, 2, 64);
            v += __shfl_xor(v, 4, 64);
            v += __shfl_xor(v, 8, 64);
            v += __shfl_xor(v, 16, 64);
            v += __shfl_xor(v, 32, 64);
            p[t] = v;
        }
        if (lane == 0) {
            float4* dpr = (float4*)&predbuf[cur][wid][0];
#pragma unroll
            for (int j2 = 0; j2 < CHUNK / 4; ++j2)
                dpr[j2] = make_float4(p[4*j2], p[4*j2+1], p[4*j2+2], p[4*j2+3]);
        }
        if (tid < WORDS && c + 1 < NCHUNK) xbf[(cur ^ 1) * CHUNK * 4 + sidx] = nv;
        __syncthreads();
        if (tid < CHUNK) {
            const float ssum = predbuf[cur][0][tid] + predbuf[cur][1][tid]
                             + predbuf[cur][2][tid] + predbuf[cur][3][tid];
            out[(size_t)b * NL + c * CHUNK + tid] = ssum + bgv;
        }
    }
}

extern "C" void kernel_launch(void* const* d_in, const int* in_sizes, int n_in,
                              void* d_out, int out_size, void* d_ws, size_t ws_size,
                              hipStream_t stream) {
    const float* x  = (const float*)d_in[0];
    const float* Wp = (const float*)d_in[1];
    const float* bp = (const float*)d_in[2];
    const float* Wz = (const float*)d_in[3];
    const float* bz = (const float*)d_in[4];
    const float* Wh = (const float*)d_in[5];
    const float* bh = (const float*)d_in[6];
    const float* Wg = (const float*)d_in[7];
    const float* bg = (const float*)d_in[8];
    float* out = (float*)d_out;

    float* wsW = (float*)d_ws;                       // 8 KB folded weights

    fold_kernel<<<4, 256, 0, stream>>>(Wp, bp, Wz, bz, Wh, bh, wsW);

    const size_t need = (size_t)(8 * NH) * sizeof(float)
                      + (size_t)2 * NB * NSEG * NH * sizeof(float);
    if (ws_size >= need) {
        float* Aarr = wsW + 8 * NH;
        float* Barr = Aarr + (size_t)NB * NSEG * NH;
        pass1_seg<<<NB * NSEG, 256, 0, stream>>>(x, wsW, Aarr, Barr);
        pass3_pred<<<NB * NSEG, 256, 0, stream>>>(x, wsW, Wg, bg, Aarr, Barr, out);
    } else {
        scan_kernel_nows<<<NB, 256, 0, stream>>>(x, wsW, Wg, bg, out);
    }
}

// Round 6
// 76.753 us; speedup vs baseline: 1.2428x; 1.2428x over previous
//
#include <hip/hip_runtime.h>

#define NB 128
#define NL 2048
#define NH 256
#define NSEG 16
#define SEGLEN (NL / NSEG)   // 128
#define RCHUNK 16            // timesteps per reduce-chunk in pass3
#define PBPITCH 9            // uints per channel row in pbuf (2-way banks)
#define CHUNK 32             // fallback kernel chunking
#define NCHUNK (NL / CHUNK)
#define WORDS (CHUNK * 3)

typedef float f32x2 __attribute__((ext_vector_type(2)));
typedef __fp16 f16x2 __attribute__((ext_vector_type(2)));   // matches cvt_pkrtz return type

__device__ __forceinline__ float fexp2(float v) { return __builtin_amdgcn_exp2f(v); }
__device__ __forceinline__ float frcp(float v)  { return __builtin_amdgcn_rcpf(v); }

__device__ __forceinline__ f32x2 pkfma(f32x2 a, f32x2 b, f32x2 c) {
#if __has_builtin(__builtin_elementwise_fma)
    return __builtin_elementwise_fma(a, b, c);   // -> v_pk_fma_f32
#else
    f32x2 r; r.x = fmaf(a.x, b.x, c.x); r.y = fmaf(a.y, b.y, c.y); return r;
#endif
}
__device__ __forceinline__ f32x2 splat2(float v) { f32x2 r; r.x = v; r.y = v; return r; }

union U32H2 { unsigned int u; f16x2 h; };

// ---------------------------------------------------------------------------
// Fold K=3 projection through Wz/Wh, pre-scaled by exp2 constants.
// ---------------------------------------------------------------------------
__global__ __launch_bounds__(256) void fold_kernel(
        const float* __restrict__ Wp, const float* __restrict__ bp,
        const float* __restrict__ Wz, const float* __restrict__ bz,
        const float* __restrict__ Wh, const float* __restrict__ bh,
        float* __restrict__ wsW) {
    const int tid = threadIdx.x;
    const int jj = tid & 63;
    const int hs = tid >> 6;                 // 0..3
    const int j = blockIdx.x * 64 + jj;
    float mz0 = 0.f, mz1 = 0.f, mz2 = 0.f, cz = 0.f;
    float mh0 = 0.f, mh1 = 0.f, mh2 = 0.f, ch = 0.f;
#pragma unroll 8
    for (int i = 0; i < 64; ++i) {
        const int h = hs * 64 + i;
        const float wz = Wz[h * NH + j];
        const float wh = Wh[h * NH + j];
        const float p0 = Wp[h];
        const float p1 = Wp[NH + h];
        const float p2 = Wp[2 * NH + h];
        const float bb = bp[h];
        mz0 = fmaf(p0, wz, mz0); mz1 = fmaf(p1, wz, mz1); mz2 = fmaf(p2, wz, mz2);
        cz  = fmaf(bb, wz, cz);
        mh0 = fmaf(p0, wh, mh0); mh1 = fmaf(p1, wh, mh1); mh2 = fmaf(p2, wh, mh2);
        ch  = fmaf(bb, wh, ch);
    }
    __shared__ float red[256][9];            // pad 9: 2-way banks
    red[tid][0] = mz0; red[tid][1] = mz1; red[tid][2] = mz2; red[tid][3] = cz;
    red[tid][4] = mh0; red[tid][5] = mh1; red[tid][6] = mh2; red[tid][7] = ch;
    __syncthreads();
    if (tid < 64) {
        float v[8];
#pragma unroll
        for (int k = 0; k < 8; ++k)
            v[k] = red[tid][k] + red[tid + 64][k] + red[tid + 128][k] + red[tid + 192][k];
        v[3] += bz[j];
        v[7] += bh[j];
        const float SZ = -1.4426950408889634f;   // -log2(e)
        const float SH = -2.8853900817779268f;   // -2*log2(e)
        float4* w4 = (float4*)(wsW + j * 8);
        w4[0] = make_float4(v[0] * SZ, v[1] * SZ, v[2] * SZ, v[3] * SZ);
        w4[1] = make_float4(v[4] * SH, v[5] * SH, v[6] * SH, v[7] * SH);
    }
}

// Gate math for 2 timesteps (packed). XQ = float4[6] (8 timesteps), U0 in 0..3.
#define GATE2(XQ, U0, AV, BV)                                                   \
    {                                                                           \
        const float* xf_ = (const float*)(XQ);                                  \
        f32x2 xx_ = { xf_[6*(U0)+0], xf_[6*(U0)+3] };                           \
        f32x2 xy_ = { xf_[6*(U0)+1], xf_[6*(U0)+4] };                           \
        f32x2 xz_ = { xf_[6*(U0)+2], xf_[6*(U0)+5] };                           \
        const f32x2 s1_ = pkfma(xx_, wax, pkfma(xy_, way, pkfma(xz_, waz, waw)));\
        const f32x2 s2_ = pkfma(xx_, wbx, pkfma(xy_, wby, pkfma(xz_, wbz, wbw)));\
        f32x2 e1_, e2_;                                                         \
        e1_.x = fexp2(s1_.x); e1_.y = fexp2(s1_.y);                             \
        e2_.x = fexp2(s2_.x); e2_.y = fexp2(s2_.y);                             \
        const f32x2 d2_ = e2_ + 1.f;                                            \
        const f32x2 e1d2_ = e1_ * d2_;                                          \
        const f32x2 dd_ = e1d2_ + d2_;                                          \
        const float rp_ = frcp(dd_.x * dd_.y);                                  \
        f32x2 rr_; rr_.x = dd_.y * rp_; rr_.y = dd_.x * rp_;                    \
        AV = e1d2_ * rr_;                                                       \
        BV = (1.f - e2_) * rr_;                                                 \
    }

#define LOAD8(XQ, SC)                                                           \
    _Pragma("unroll")                                                           \
    for (int i_ = 0; i_ < 6; ++i_) XQ[i_] = xs4[(SC) * 6 + i_];

// ---------------------------------------------------------------------------
// Pass 1: per-(batch, segment) blocks of 256 threads (thread = channel).
// Segment composite (A, B): h_end = A*h_start + B. x via L1-broadcast loads,
// double-buffered 8-timestep sub-chunks (all reg-resident, compile-time idx).
// ---------------------------------------------------------------------------
__global__ __launch_bounds__(256, 4) void pass1_seg(
        const float* __restrict__ x, const float* __restrict__ wsW,
        float* __restrict__ Aarr, float* __restrict__ Barr) {
    const int tid = threadIdx.x;
    const int b = blockIdx.x >> 4;
    const int s = blockIdx.x & (NSEG - 1);

    const float4* wv = (const float4*)(wsW + tid * 8);
    const float4 wA4 = wv[0];
    const float4 wB4 = wv[1];
    const f32x2 wax = splat2(wA4.x), way = splat2(wA4.y), waz = splat2(wA4.z), waw = splat2(wA4.w);
    const f32x2 wbx = splat2(wB4.x), wby = splat2(wB4.y), wbz = splat2(wB4.z), wbw = splat2(wB4.w);

    const float4* xs4 = (const float4*)(x + ((size_t)b * NL + (size_t)s * SEGLEN) * 3);

#define P1_BODY(XQ)                                                             \
    _Pragma("unroll")                                                           \
    for (int u0 = 0; u0 < 4; ++u0) {                                            \
        f32x2 av, bv;                                                           \
        GATE2(XQ, u0, av, bv);                                                  \
        Bacc = fmaf(av.x, Bacc, bv.x);                                          \
        Bacc = fmaf(av.y, Bacc, bv.y);                                          \
        A *= av.x * av.y;                                                       \
    }

    float A = 1.f, Bacc = 0.f;
    float4 xa[6], xb[6];
    LOAD8(xa, 0);
    for (int c = 0; c < 8; ++c) {            // 16 timesteps per iter
        LOAD8(xb, 2 * c + 1);
        P1_BODY(xa);
        const int nxt = (c < 7) ? (2 * c + 2) : 0;   // guard (uniform)
        LOAD8(xa, nxt);
        P1_BODY(xb);
    }
    const size_t o = ((size_t)b * NSEG + s) * NH + tid;
    Aarr[o] = A;
    Barr[o] = Bacc;
#undef P1_BODY
}

// ---------------------------------------------------------------------------
// Pass 3: per-(batch, segment) blocks. Computes its own segment-start state
// from (A,B) prefixes, recomputes in-segment recurrence, emits preds.
// Pred-reduction over 256 channels via f16x2-packed LDS transpose per 16 t.
// ---------------------------------------------------------------------------
__global__ __launch_bounds__(256, 4) void pass3_pred(
        const float* __restrict__ x, const float* __restrict__ wsW,
        const float* __restrict__ Wg, const float* __restrict__ bg,
        const float* __restrict__ Aarr, const float* __restrict__ Barr,
        float* __restrict__ out) {
    const int tid = threadIdx.x;
    const int b = blockIdx.x >> 4;
    const int s = blockIdx.x & (NSEG - 1);

    const float4* wv = (const float4*)(wsW + tid * 8);
    const float4 wA4 = wv[0];
    const float4 wB4 = wv[1];
    const f32x2 wax = splat2(wA4.x), way = splat2(wA4.y), waz = splat2(wA4.z), waw = splat2(wA4.w);
    const f32x2 wbx = splat2(wB4.x), wby = splat2(wB4.y), wbz = splat2(wB4.z), wbw = splat2(wB4.w);
    const float wg = Wg[tid];
    const float bgv = bg[0];

    // ---- segment-start state: prefix over earlier segments' (A,B) ----
    float h = 0.f;
    {
        const size_t pbase = (size_t)b * NSEG * NH + tid;
        for (int k0 = 0; k0 < NSEG; k0 += 8) {
            float Ak[8], Bk[8];
#pragma unroll
            for (int k = 0; k < 8; ++k) {
                const int kk = k0 + k;                 // uniform predicate
                Ak[k] = (kk < s) ? Aarr[pbase + (size_t)kk * NH] : 1.f;
                Bk[k] = (kk < s) ? Barr[pbase + (size_t)kk * NH] : 0.f;
            }
#pragma unroll
            for (int k = 0; k < 8; ++k) h = fmaf(Ak[k], h, Bk[k]);
        }
    }

    const float4* xs4 = (const float4*)(x + ((size_t)b * NL + (size_t)s * SEGLEN) * 3);

    __shared__ unsigned int pbuf[NH * PBPITCH];   // f16x2 pairs, 9216 B
    __shared__ float part2[32][18];               // [grp][t]
    __shared__ float part3[4][17];

    const int q   = tid & 7;                 // stage2: timestep-pair index
    const int grp = tid >> 3;                // stage2: channel group (8 ch)

#define P3_BODY(XQ, Q0)                                                         \
    _Pragma("unroll")                                                           \
    for (int u0 = 0; u0 < 4; ++u0) {                                            \
        f32x2 av, bv;                                                           \
        GATE2(XQ, u0, av, bv);                                                  \
        const float p0_ = h * wg;            /* pred uses h BEFORE update */    \
        h = fmaf(av.x, h, bv.x);                                                \
        const float p1_ = h * wg;                                               \
        h = fmaf(av.y, h, bv.y);                                                \
        U32H2 pk_; pk_.h = __builtin_amdgcn_cvt_pkrtz(p0_, p1_);                \
        pk[(Q0) + u0] = pk_.u;                                                  \
    }

    float4 xa[6], xb[6];
    unsigned int pk[8];
    LOAD8(xa, 0);
    for (int c = 0; c < 8; ++c) {            // 16 timesteps per iter
        LOAD8(xb, 2 * c + 1);
        P3_BODY(xa, 0);
        const int nxt = (c < 7) ? (2 * c + 2) : 0;
        LOAD8(xa, nxt);
        P3_BODY(xb, 4);

        // stage 1: 8 b32 writes (pitch 9 -> 2-way banks = free)
#pragma unroll
        for (int v = 0; v < 8; ++v) pbuf[tid * PBPITCH + v] = pk[v];
        __syncthreads();
        // stage 2: each thread sums 8 channels for one t-pair (pk_add_f16)
        f16x2 acc2 = (f16x2)0.f;
#pragma unroll
        for (int j = 0; j < 8; ++j) {
            const int c2 = grp * 8 + ((j + grp) & 7);    // rotation
            U32H2 rd; rd.u = pbuf[c2 * PBPITCH + q];
            acc2 += rd.h;
        }
        {
            f32x2 pr; pr.x = (float)acc2.x; pr.y = (float)acc2.y;
            *(f32x2*)&part2[grp][2 * q] = pr;            // b64 store
        }
        __syncthreads();
        // stage 3a: wave 0 reduces 32 groups -> 4 quads; 3b: final + bias
        if (tid < 64) {
            const int t2 = tid & 15, quad = tid >> 4;
            float a3 = 0.f;
#pragma unroll
            for (int g2 = 0; g2 < 8; ++g2)
                a3 += part2[quad * 8 + g2][t2];
            part3[quad][t2] = a3;
            if (tid < 16) {
                const float o = part3[0][tid] + part3[1][tid]
                              + part3[2][tid] + part3[3][tid] + bgv;
                out[(size_t)b * NL + (size_t)s * SEGLEN + c * RCHUNK + tid] = o;
            }
        }
        // pbuf overwrite (next stage1) is fenced for all waves by the second
        // barrier above; part2 rewrite happens only after the next first barrier.
    }
#undef P3_BODY
}

// ---------------------------------------------------------------------------
// Fallback (ws too small): monolithic scan, 128 blocks x 256 thr.
// ---------------------------------------------------------------------------
__global__ __launch_bounds__(256) void scan_kernel_nows(
        const float* __restrict__ x, const float* __restrict__ wsW,
        const float* __restrict__ Wg, const float* __restrict__ bg,
        float* __restrict__ out) {
    const int tid  = threadIdx.x;
    const int lane = tid & 63;
    const int wid  = tid >> 6;
    const int b = blockIdx.x;

    const float4* wv = (const float4*)(wsW + tid * 8);
    const float4 wA = wv[0];
    const float4 wB = wv[1];
    const float  wg = Wg[tid];
    const float  bgv = bg[0];

    const float* xb = x + (size_t)b * (NL * 3);

    __shared__ float4 xbuf[2][CHUNK];
    __shared__ float  predbuf[2][4][CHUNK];
    float* xbf = (float*)xbuf;

    const int sw = tid;
    const int sidx = (sw / 3) * 4 + (sw % 3);

    if (tid < WORDS) xbf[sidx] = xb[sw];
    __syncthreads();

    float h = 0.f;
    for (int c = 0; c < NCHUNK; ++c) {
        const int cur = c & 1;
        float nv = 0.f;
        if (tid < WORDS && c + 1 < NCHUNK) nv = xb[(c + 1) * WORDS + sw];

        float p[CHUNK];
        const float4* xc = xbuf[cur];
#pragma unroll
        for (int t = 0; t < CHUNK; ++t) {
            const float4 xv = xc[t];
            const float e1 = fexp2(fmaf(xv.x, wA.x, fmaf(xv.y, wA.y, fmaf(xv.z, wA.z, wA.w))));
            const float e2 = fexp2(fmaf(xv.x, wB.x, fmaf(xv.y, wB.y, fmaf(xv.z, wB.z, wB.w))));
            const float d2 = 1.f + e2;
            const float e1d2 = e1 * d2;
            const float r  = frcp(e1d2 + d2);
            p[t] = h * wg;
            h = fmaf(e1d2 * r, h, (1.f - e2) * r);
        }
#pragma unroll
        for (int t = 0; t < CHUNK; ++t) {
            float v = p[t];
            v += __shfl_xor(v, 1, 64);
            v += __shfl_xor(v, 2, 64);
            v += __shfl_xor(v, 4, 64);
            v += __shfl_xor(v, 8, 64);
            v += __shfl_xor(v, 16, 64);
            v += __shfl_xor(v, 32, 64);
            p[t] = v;
        }
        if (lane == 0) {
            float4* dpr = (float4*)&predbuf[cur][wid][0];
#pragma unroll
            for (int j2 = 0; j2 < CHUNK / 4; ++j2)
                dpr[j2] = make_float4(p[4*j2], p[4*j2+1], p[4*j2+2], p[4*j2+3]);
        }
        if (tid < WORDS && c + 1 < NCHUNK) xbf[(cur ^ 1) * CHUNK * 4 + sidx] = nv;
        __syncthreads();
        if (tid < CHUNK) {
            const float ssum = predbuf[cur][0][tid] + predbuf[cur][1][tid]
                             + predbuf[cur][2][tid] + predbuf[cur][3][tid];
            out[(size_t)b * NL + c * CHUNK + tid] = ssum + bgv;
        }
    }
}

extern "C" void kernel_launch(void* const* d_in, const int* in_sizes, int n_in,
                              void* d_out, int out_size, void* d_ws, size_t ws_size,
                              hipStream_t stream) {
    const float* x  = (const float*)d_in[0];
    const float* Wp = (const float*)d_in[1];
    const float* bp = (const float*)d_in[2];
    const float* Wz = (const float*)d_in[3];
    const float* bz = (const float*)d_in[4];
    const float* Wh = (const float*)d_in[5];
    const float* bh = (const float*)d_in[6];
    const float* Wg = (const float*)d_in[7];
    const float* bg = (const float*)d_in[8];
    float* out = (float*)d_out;

    float* wsW = (float*)d_ws;                       // 8 KB folded weights

    fold_kernel<<<4, 256, 0, stream>>>(Wp, bp, Wz, bz, Wh, bh, wsW);

    const size_t need = (size_t)(8 * NH) * sizeof(float)
                      + (size_t)2 * NB * NSEG * NH * sizeof(float);
    if (ws_size >= need) {
        float* Aarr = wsW + 8 * NH;
        float* Barr = Aarr + (size_t)NB * NSEG * NH;
        pass1_seg<<<NB * NSEG, 256, 0, stream>>>(x, wsW, Aarr, Barr);
        pass3_pred<<<NB * NSEG, 256, 0, stream>>>(x, wsW, Wg, bg, Aarr, Barr, out);
    } else {
        scan_kernel_nows<<<NB, 256, 0, stream>>>(x, wsW, Wg, bg, out);
    }
}